// Round 13
// baseline (26.189 us; speedup 1.0000x reference)
//
#include <hip/hip_runtime.h>

#define EPS 1e-8f
constexpr int Bn = 8192, Ln = 512, Kn = 4;
constexpr int EPT = Ln / 64;       // 8 elements per lane per row
constexpr int WS_STRIDE = 16;      // floats per row in ws: mu[4] isig[4] logc[4] mean var pad pad

typedef float f32x4 __attribute__((ext_vector_type(4)));

// ---------------- Kernel 1: per-row stats + component constants ----------------
__global__ __launch_bounds__(256, 8) void stats_kernel(
    const float* __restrict__ windows,
    const float* __restrict__ noise,
    const float* __restrict__ init_centers,
    const float* __restrict__ init_scales,
    const float* __restrict__ init_weights,
    float* __restrict__ ws)
{
    const int wave = threadIdx.x >> 6;
    const int lane = threadIdx.x & 63;
    const int row  = blockIdx.x * 4 + wave;

    const float* xr = windows + (size_t)row * Ln;
    float x[EPT];
    #pragma unroll
    for (int j = 0; j < EPT; ++j) x[j] = xr[lane + 64 * j];

    float s = 0.f, sq = 0.f;
    #pragma unroll
    for (int j = 0; j < EPT; ++j) { s += x[j]; sq = fmaf(x[j], x[j], sq); }
    #pragma unroll
    for (int off = 32; off; off >>= 1) {
        s  += __shfl_xor(s,  off, 64);
        sq += __shfl_xor(sq, off, 64);
    }
    const float mean = s * (1.0f / (float)Ln);
    float var = (sq - s * s * (1.0f / (float)Ln)) * (1.0f / (float)(Ln - 1));
    var = fmaxf(var, 0.f);
    const float stdv = sqrtf(var);

    if (lane < Kn) {
        const int k  = lane;
        float m  = fmaf(init_centers[k], stdv, mean) + noise[(size_t)row * Kn + k] * stdv * 0.01f;
        float is = 1.0f / (fabsf(init_scales[k]) * stdv + EPS);
        float lc = __logf((init_weights[k] + EPS) * is);
        float* wr = ws + (size_t)row * WS_STRIDE;
        wr[k]     = m;
        wr[4 + k] = is;
        wr[8 + k] = lc;
        if (k == 0) { wr[12] = mean; wr[13] = var; }
    }
}

// ------- Kernel 2: streaming pass, occupancy-limited for a MOVING write window -------
// __launch_bounds__(256,2): 2 blocks/CU resident -> 4 generations over 2048 blocks.
// Active write front ~16 MB instead of all 67 MB at once; generations de-phase so
// some waves always issue stores while others load/compute.
__global__ __launch_bounds__(256, 2) void stream_kernel(
    const float* __restrict__ windows,
    const float* __restrict__ log_weights,
    const float* __restrict__ prior_w_param,
    const float* __restrict__ blend_param,
    const float* __restrict__ ws,
    float* __restrict__ g_out,      // B*L*K
    float* __restrict__ p_out,      // B*K
    float* __restrict__ a_out,      // B*K
    float* __restrict__ b_out)      // B*K
{
    const int wave = threadIdx.x >> 6;
    const int lane = threadIdx.x & 63;
    // XCD-chunked bijective swizzle: 2048 blocks = 8 XCDs x 256 (exact)
    const int swz  = (blockIdx.x & 7) * (2048 / 8) + (blockIdx.x >> 3);
    const int row  = swz * 4 + wave;

    // broadcast constant loads (wave-uniform address)
    const float* wr = ws + (size_t)row * WS_STRIDE;
    const f32x4 cmu = *reinterpret_cast<const f32x4*>(wr);
    const f32x4 cis = *reinterpret_cast<const f32x4*>(wr + 4);
    const f32x4 clc = *reinterpret_cast<const f32x4*>(wr + 8);
    const f32x4 cmv = *reinterpret_cast<const f32x4*>(wr + 12);

    const float* xr = windows + (size_t)row * Ln;
    float x[EPT], wl[EPT];
    #pragma unroll
    for (int j = 0; j < EPT; ++j) x[j]  = xr[lane + 64 * j];
    #pragma unroll
    for (int j = 0; j < EPT; ++j) wl[j] = log_weights[lane + 64 * j];

    const float pw = 1.0f / (1.0f + __expf(-prior_w_param[0]));
    const float bl = 1.0f / (1.0f + __expf(-blend_param[0]));

    #pragma unroll
    for (int j = 0; j < EPT; ++j) wl[j] = __expf(wl[j]);

    float mu[Kn]      = {cmu.x, cmu.y, cmu.z, cmu.w};
    float inv_sig[Kn] = {cis.x, cis.y, cis.z, cis.w};
    float logc[Kn]    = {clc.x, clc.y, clc.z, clc.w};
    const float mean = cmv.x, var = cmv.y;

    float s0[Kn] = {0,0,0,0}, s1[Kn] = {0,0,0,0}, s2[Kn] = {0,0,0,0};

    #pragma unroll
    for (int j = 0; j < EPT; ++j) {
        const int   l  = lane + 64 * j;
        const float xv = x[j];
        float lm[Kn];
        float mx = -1e30f;
        #pragma unroll
        for (int k = 0; k < Kn; ++k) {
            float t = (xv - mu[k]) * inv_sig[k];
            lm[k] = fmaf(t * t, -0.5f, logc[k]);
            mx = fmaxf(mx, lm[k]);
        }
        float e[Kn], sum = 0.f;
        #pragma unroll
        for (int k = 0; k < Kn; ++k) { e[k] = __expf(lm[k] - mx); sum += e[k]; }
        float inv = 1.0f / sum;
        f32x4 gv;
        gv.x = e[0] * inv; gv.y = e[1] * inv; gv.z = e[2] * inv; gv.w = e[3] * inv;
        reinterpret_cast<f32x4*>(g_out)[(size_t)row * Ln + l] = gv;

        float c   = wl[j] * inv;
        float xc  = xv * c;
        float x2c = xv * xc;
        #pragma unroll
        for (int k = 0; k < Kn; ++k) {
            s0[k] = fmaf(e[k], c,   s0[k]);
            s1[k] = fmaf(e[k], xc,  s1[k]);
            s2[k] = fmaf(e[k], x2c, s2[k]);
        }
    }

    #pragma unroll
    for (int off = 32; off; off >>= 1)
        #pragma unroll
        for (int k = 0; k < Kn; ++k) {
            s0[k] += __shfl_xor(s0[k], off, 64);
            s1[k] += __shfl_xor(s1[k], off, 64);
            s2[k] += __shfl_xor(s2[k], off, 64);
        }

    if (lane < Kn) {
        const int k = lane;
        float psum = 0.f;
        #pragma unroll
        for (int kk = 0; kk < Kn; ++kk) psum += fmaxf(s0[kk], EPS) + pw;
        float sg   = fmaxf(s0[k], EPS);
        float dmu  = s1[k] / sg;
        float av   = dmu * bl + mean * (1.0f - bl);
        float dvar = (s2[k] - 2.0f * av * s1[k] + av * av * s0[k]) / sg;
        float bv   = sqrtf(dvar * bl + var * (1.0f - bl) + EPS);
        p_out[(size_t)row * Kn + k] = (sg + pw) / psum;
        a_out[(size_t)row * Kn + k] = av;
        b_out[(size_t)row * Kn + k] = bv;
    }
}

// ---------------- Fallback: round-8 fused kernel (proven 24.3 us) ----------------
__global__ __launch_bounds__(256, 4) void em_kernel_fused(
    const float* __restrict__ windows,
    const float* __restrict__ noise,
    const float* __restrict__ init_centers,
    const float* __restrict__ init_scales,
    const float* __restrict__ init_weights,
    const float* __restrict__ prior_w_param,
    const float* __restrict__ log_weights,
    const float* __restrict__ blend_param,
    float* __restrict__ g_out,
    float* __restrict__ p_out,
    float* __restrict__ a_out,
    float* __restrict__ b_out)
{
    const int wave = threadIdx.x >> 6;
    const int lane = threadIdx.x & 63;
    const int gw   = blockIdx.x * 4 + wave;
    const int rowA = gw * 2;
    const int rowB = rowA + 1;

    float xA[EPT], xB[EPT], wl[EPT];
    const float* xrowA = windows + (size_t)rowA * Ln;
    const float* xrowB = windows + (size_t)rowB * Ln;
    #pragma unroll
    for (int j = 0; j < EPT; ++j) xA[j] = xrowA[lane + 64 * j];
    #pragma unroll
    for (int j = 0; j < EPT; ++j) xB[j] = xrowB[lane + 64 * j];
    #pragma unroll
    for (int j = 0; j < EPT; ++j) wl[j] = log_weights[lane + 64 * j];
    float nzA[Kn], nzB[Kn];
    #pragma unroll
    for (int k = 0; k < Kn; ++k) nzA[k] = noise[(size_t)rowA * Kn + k];
    #pragma unroll
    for (int k = 0; k < Kn; ++k) nzB[k] = noise[(size_t)rowB * Kn + k];

    const float pw = 1.0f / (1.0f + __expf(-prior_w_param[0]));
    const float bl = 1.0f / (1.0f + __expf(-blend_param[0]));

    #pragma unroll
    for (int j = 0; j < EPT; ++j) wl[j] = __expf(wl[j]);

    #pragma unroll
    for (int r = 0; r < 2; ++r) {
        const int    row = (r == 0) ? rowA : rowB;
        const float* x   = (r == 0) ? xA   : xB;
        const float* nz  = (r == 0) ? nzA  : nzB;

        float s = 0.f, sq = 0.f;
        #pragma unroll
        for (int j = 0; j < EPT; ++j) { s += x[j]; sq = fmaf(x[j], x[j], sq); }
        #pragma unroll
        for (int off = 32; off; off >>= 1) {
            s  += __shfl_xor(s,  off, 64);
            sq += __shfl_xor(sq, off, 64);
        }
        const float mean = s * (1.0f / (float)Ln);
        float var = (sq - s * s * (1.0f / (float)Ln)) * (1.0f / (float)(Ln - 1));
        var = fmaxf(var, 0.f);
        const float stdv = sqrtf(var);

        float mu[Kn], inv_sig[Kn], logc[Kn];
        #pragma unroll
        for (int k = 0; k < Kn; ++k) {
            float m  = fmaf(init_centers[k], stdv, mean) + nz[k] * stdv * 0.01f;
            float is = 1.0f / (fabsf(init_scales[k]) * stdv + EPS);
            mu[k]      = m;
            inv_sig[k] = is;
            logc[k]    = __logf((init_weights[k] + EPS) * is);
        }

        float s0[Kn] = {0,0,0,0}, s1[Kn] = {0,0,0,0}, s2[Kn] = {0,0,0,0};
        #pragma unroll
        for (int j = 0; j < EPT; ++j) {
            const int   l  = lane + 64 * j;
            const float xv = x[j];
            float lm[Kn];
            float mx = -1e30f;
            #pragma unroll
            for (int k = 0; k < Kn; ++k) {
                float t = (xv - mu[k]) * inv_sig[k];
                lm[k] = fmaf(t * t, -0.5f, logc[k]);
                mx = fmaxf(mx, lm[k]);
            }
            float e[Kn], sum = 0.f;
            #pragma unroll
            for (int k = 0; k < Kn; ++k) { e[k] = __expf(lm[k] - mx); sum += e[k]; }
            float inv = 1.0f / sum;
            f32x4 gv;
            gv.x = e[0] * inv; gv.y = e[1] * inv; gv.z = e[2] * inv; gv.w = e[3] * inv;
            reinterpret_cast<f32x4*>(g_out)[(size_t)row * Ln + l] = gv;

            float c   = wl[j] * inv;
            float xc  = xv * c;
            float x2c = xv * xc;
            #pragma unroll
            for (int k = 0; k < Kn; ++k) {
                s0[k] = fmaf(e[k], c,   s0[k]);
                s1[k] = fmaf(e[k], xc,  s1[k]);
                s2[k] = fmaf(e[k], x2c, s2[k]);
            }
        }

        #pragma unroll
        for (int off = 32; off; off >>= 1)
            #pragma unroll
            for (int k = 0; k < Kn; ++k) {
                s0[k] += __shfl_xor(s0[k], off, 64);
                s1[k] += __shfl_xor(s1[k], off, 64);
                s2[k] += __shfl_xor(s2[k], off, 64);
            }

        if (lane < Kn) {
            const int k = lane;
            float psum = 0.f;
            #pragma unroll
            for (int kk = 0; kk < Kn; ++kk) psum += fmaxf(s0[kk], EPS) + pw;
            float sg   = fmaxf(s0[k], EPS);
            float dmu  = s1[k] / sg;
            float av   = dmu * bl + mean * (1.0f - bl);
            float dvar = (s2[k] - 2.0f * av * s1[k] + av * av * s0[k]) / sg;
            float bv   = sqrtf(dvar * bl + var * (1.0f - bl) + EPS);
            p_out[(size_t)row * Kn + k] = (sg + pw) / psum;
            a_out[(size_t)row * Kn + k] = av;
            b_out[(size_t)row * Kn + k] = bv;
        }
    }
}

extern "C" void kernel_launch(void* const* d_in, const int* in_sizes, int n_in,
                              void* d_out, int out_size, void* d_ws, size_t ws_size,
                              hipStream_t stream) {
    const float* windows       = (const float*)d_in[0];
    const float* noise         = (const float*)d_in[1];
    const float* init_centers  = (const float*)d_in[2];
    const float* init_scales   = (const float*)d_in[3];
    const float* init_weights  = (const float*)d_in[4];
    const float* prior_w_param = (const float*)d_in[5];
    const float* log_weights   = (const float*)d_in[6];
    const float* blend_param   = (const float*)d_in[7];

    float* out = (float*)d_out;
    const size_t G  = (size_t)Bn * Ln * Kn;   // 16,777,216
    const size_t BK = (size_t)Bn * Kn;        // 32,768
    float* g_out = out;
    float* p_out = out + G;
    float* a_out = out + G + BK;
    float* b_out = out + G + 2 * BK;

    const size_t ws_need = (size_t)Bn * WS_STRIDE * sizeof(float);   // 512 KB
    if (ws_size >= ws_need) {
        float* ws = (float*)d_ws;
        stats_kernel<<<dim3(Bn / 4), dim3(256), 0, stream>>>(
            windows, noise, init_centers, init_scales, init_weights, ws);
        stream_kernel<<<dim3(Bn / 4), dim3(256), 0, stream>>>(
            windows, log_weights, prior_w_param, blend_param, ws,
            g_out, p_out, a_out, b_out);
    } else {
        em_kernel_fused<<<dim3(Bn / 8), dim3(256), 0, stream>>>(
            windows, noise, init_centers, init_scales, init_weights,
            prior_w_param, log_weights, blend_param,
            g_out, p_out, a_out, b_out);
    }
}

// Round 15
// 24.152 us; speedup vs baseline: 1.0843x; 1.0843x over previous
//
#include <hip/hip_runtime.h>

#define EPS 1e-8f
constexpr int Bn = 8192, Ln = 512, Kn = 4;
constexpr int EPT = Ln / 64;   // 8 elements per lane per row

typedef float f32x4 __attribute__((ext_vector_type(4)));

// ---- DPP wave64 sum: VALU-pipe only (no LDS crossbar), ~4cyc/step ----
template<int CTRL>
__device__ __forceinline__ float dpp_add(float x) {
    union { float f; int i; } u, r;
    u.f = x;
    // old=0 so OOB/non-updated lanes contribute +0 under either bound_ctrl semantic
    r.i = __builtin_amdgcn_update_dpp(0, u.i, CTRL, 0xF, 0xF, true);
    return x + r.f;
}

__device__ __forceinline__ float wave_sum_bcast(float x) {
    x = dpp_add<0x111>(x);   // row_shr:1
    x = dpp_add<0x112>(x);   // row_shr:2
    x = dpp_add<0x114>(x);   // row_shr:4
    x = dpp_add<0x118>(x);   // row_shr:8  -> lane15/31/47/63 hold row sums
    x = dpp_add<0x142>(x);   // row_bcast:15 -> lane31/63 hold half sums
    x = dpp_add<0x143>(x);   // row_bcast:31 -> lane63 holds total
    union { float f; int i; } u;
    u.f = x;
    u.i = __builtin_amdgcn_readlane(u.i, 63);   // broadcast via SGPR
    return u.f;
}

__global__ __launch_bounds__(256, 4) void em_kernel(
    const float* __restrict__ windows,
    const float* __restrict__ noise,
    const float* __restrict__ init_centers,
    const float* __restrict__ init_scales,
    const float* __restrict__ init_weights,
    const float* __restrict__ prior_w_param,
    const float* __restrict__ log_weights,
    const float* __restrict__ blend_param,
    float* __restrict__ g_out,      // B*L*K
    float* __restrict__ p_out,      // B*K
    float* __restrict__ a_out,      // B*K
    float* __restrict__ b_out)      // B*K
{
    const int wave = threadIdx.x >> 6;
    const int lane = threadIdx.x & 63;
    const int gw   = blockIdx.x * 4 + wave;
    const int rowA = gw * 2;
    const int rowB = rowA + 1;

    // ---- issue ALL global loads up front ----
    float xA[EPT], xB[EPT], wl[EPT];
    const float* xrowA = windows + (size_t)rowA * Ln;
    const float* xrowB = windows + (size_t)rowB * Ln;
    #pragma unroll
    for (int j = 0; j < EPT; ++j) xA[j] = xrowA[lane + 64 * j];
    #pragma unroll
    for (int j = 0; j < EPT; ++j) xB[j] = xrowB[lane + 64 * j];
    #pragma unroll
    for (int j = 0; j < EPT; ++j) wl[j] = log_weights[lane + 64 * j];
    float nzA[Kn], nzB[Kn];
    #pragma unroll
    for (int k = 0; k < Kn; ++k) nzA[k] = noise[(size_t)rowA * Kn + k];
    #pragma unroll
    for (int k = 0; k < Kn; ++k) nzB[k] = noise[(size_t)rowB * Kn + k];

    const float pw = 1.0f / (1.0f + __expf(-prior_w_param[0]));
    const float bl = 1.0f / (1.0f + __expf(-blend_param[0]));

    #pragma unroll
    for (int j = 0; j < EPT; ++j) wl[j] = __expf(wl[j]);

    #pragma unroll
    for (int r = 0; r < 2; ++r) {
        const int    row = (r == 0) ? rowA : rowB;
        const float* x   = (r == 0) ? xA   : xB;
        const float* nz  = (r == 0) ? nzA  : nzB;

        // ---- pass A: mean / var(ddof=1) via DPP (VALU pipe) ----
        float sp = 0.f, sqp = 0.f;
        #pragma unroll
        for (int j = 0; j < EPT; ++j) { sp += x[j]; sqp = fmaf(x[j], x[j], sqp); }
        const float S  = wave_sum_bcast(sp);
        const float SQ = wave_sum_bcast(sqp);
        const float mean = S * (1.0f / (float)Ln);
        float var = (SQ - S * S * (1.0f / (float)Ln)) * (1.0f / (float)(Ln - 1));
        var = fmaxf(var, 0.f);
        const float stdv = sqrtf(var);

        // ---- per-component constants ----
        float mu[Kn], inv_sig[Kn], logc[Kn];
        #pragma unroll
        for (int k = 0; k < Kn; ++k) {
            float m  = fmaf(init_centers[k], stdv, mean) + nz[k] * stdv * 0.01f;
            float is = 1.0f / (fabsf(init_scales[k]) * stdv + EPS);
            mu[k]      = m;
            inv_sig[k] = is;
            logc[k]    = __logf((init_weights[k] + EPS) * is);
        }

        // ---- pass B: softmax responsibilities + weighted moments ----
        float s0[Kn] = {0,0,0,0}, s1[Kn] = {0,0,0,0}, s2[Kn] = {0,0,0,0};

        #pragma unroll
        for (int j = 0; j < EPT; ++j) {
            const int   l  = lane + 64 * j;
            const float xv = x[j];
            float lm[Kn];
            float mx = -1e30f;
            #pragma unroll
            for (int k = 0; k < Kn; ++k) {
                float t = (xv - mu[k]) * inv_sig[k];
                lm[k] = fmaf(t * t, -0.5f, logc[k]);
                mx = fmaxf(mx, lm[k]);
            }
            float e[Kn], sum = 0.f;
            #pragma unroll
            for (int k = 0; k < Kn; ++k) { e[k] = __expf(lm[k] - mx); sum += e[k]; }
            float inv = 1.0f / sum;
            f32x4 gv;
            gv.x = e[0] * inv; gv.y = e[1] * inv; gv.z = e[2] * inv; gv.w = e[3] * inv;
            reinterpret_cast<f32x4*>(g_out)[(size_t)row * Ln + l] = gv;

            float c   = wl[j] * inv;
            float xc  = xv * c;
            float x2c = xv * xc;
            #pragma unroll
            for (int k = 0; k < Kn; ++k) {
                s0[k] = fmaf(e[k], c,   s0[k]);
                s1[k] = fmaf(e[k], xc,  s1[k]);
                s2[k] = fmaf(e[k], x2c, s2[k]);
            }
        }

        // ---- moment reductions via DPP: 12 independent VALU chains ----
        #pragma unroll
        for (int k = 0; k < Kn; ++k) {
            s0[k] = wave_sum_bcast(s0[k]);
            s1[k] = wave_sum_bcast(s1[k]);
            s2[k] = wave_sum_bcast(s2[k]);
        }

        // ---- epilogue: uniform math, lane 0 stores 16B vectors ----
        float psum = 0.f;
        #pragma unroll
        for (int kk = 0; kk < Kn; ++kk) psum += fmaxf(s0[kk], EPS) + pw;
        const float invp = 1.0f / psum;
        float pk[Kn], av[Kn], bvv[Kn];
        #pragma unroll
        for (int k = 0; k < Kn; ++k) {
            float sg   = fmaxf(s0[k], EPS);
            float dmu  = s1[k] / sg;
            float a    = dmu * bl + mean * (1.0f - bl);
            float dvar = (s2[k] - 2.0f * a * s1[k] + a * a * s0[k]) / sg;
            float b    = sqrtf(dvar * bl + var * (1.0f - bl) + EPS);
            pk[k]  = (sg + pw) * invp;
            av[k]  = a;
            bvv[k] = b;
        }
        if (lane == 0) {
            f32x4 pv = {pk[0],  pk[1],  pk[2],  pk[3]};
            f32x4 avv = {av[0],  av[1],  av[2],  av[3]};
            f32x4 bv = {bvv[0], bvv[1], bvv[2], bvv[3]};
            *reinterpret_cast<f32x4*>(p_out + (size_t)row * Kn) = pv;
            *reinterpret_cast<f32x4*>(a_out + (size_t)row * Kn) = avv;
            *reinterpret_cast<f32x4*>(b_out + (size_t)row * Kn) = bv;
        }
    }
}

extern "C" void kernel_launch(void* const* d_in, const int* in_sizes, int n_in,
                              void* d_out, int out_size, void* d_ws, size_t ws_size,
                              hipStream_t stream) {
    const float* windows       = (const float*)d_in[0];
    const float* noise         = (const float*)d_in[1];
    const float* init_centers  = (const float*)d_in[2];
    const float* init_scales   = (const float*)d_in[3];
    const float* init_weights  = (const float*)d_in[4];
    const float* prior_w_param = (const float*)d_in[5];
    const float* log_weights   = (const float*)d_in[6];
    const float* blend_param   = (const float*)d_in[7];

    float* out = (float*)d_out;
    const size_t G  = (size_t)Bn * Ln * Kn;   // 16,777,216
    const size_t BK = (size_t)Bn * Kn;        // 32,768
    float* g_out = out;
    float* p_out = out + G;
    float* a_out = out + G + BK;
    float* b_out = out + G + 2 * BK;

    em_kernel<<<dim3(Bn / 8), dim3(256), 0, stream>>>(   // 1024 blocks, 2 rows/wave
        windows, noise, init_centers, init_scales, init_weights,
        prior_w_param, log_weights, blend_param,
        g_out, p_out, a_out, b_out);
}